// Round 1
// baseline (531.211 us; speedup 1.0000x reference)
//
#include <hip/hip_runtime.h>
#include <hip/hip_bf16.h>

// AGNN 2-layer encoder: N=50000 nodes, E=850000 edges (w/ self-loops), D=H=128.
// Pipeline: detect edge dtype -> build CSR (by dst) once ->
//   [gemm+rownorm -> fused attn-aggregate(+relu)] x 2 layers.

#define FDIM 128

// ---------------- edge dtype probe: int64 => odd 32-bit words are all 0 ----
__global__ void detect_kernel(const int* __restrict__ ei, int* __restrict__ flag) {
  if (threadIdx.x == 0 && blockIdx.x == 0) {
    int all0 = 1;
    for (int i = 1; i < 64; i += 2) all0 &= (ei[i] == 0);
    *flag = all0;  // 1 => int64 layout, 0 => int32
  }
}

// ---------------- normalize edges to int32 + per-dst histogram -------------
__global__ __launch_bounds__(256) void convert_count_kernel(
    const void* __restrict__ ei, const int* __restrict__ flag, int E,
    int* __restrict__ src32, int* __restrict__ dst32, int* __restrict__ counts) {
  int e = blockIdx.x * 256 + threadIdx.x;
  if (e >= E) return;
  int s, d;
  if (*flag) {
    const long long* p = (const long long*)ei;
    s = (int)p[e]; d = (int)p[E + e];
  } else {
    const int* p = (const int*)ei;
    s = p[e]; d = p[E + e];
  }
  src32[e] = s; dst32[e] = d;
  atomicAdd(&counts[d], 1);
}

// ---------------- single-block exclusive scan (wave-level, few barriers) ---
__global__ __launch_bounds__(1024) void scan_kernel(
    const int* __restrict__ counts, int* __restrict__ offsets,
    int* __restrict__ cursor, int N, int E) {
  __shared__ int wsum[16];
  __shared__ int carry_s;
  int tid = threadIdx.x, lane = tid & 63, wv = tid >> 6;
  if (tid == 0) carry_s = 0;
  __syncthreads();
  for (int base = 0; base < N; base += 1024) {
    int i = base + tid;
    int v = (i < N) ? counts[i] : 0;
    int x = v;
    #pragma unroll
    for (int off = 1; off < 64; off <<= 1) {
      int t = __shfl_up(x, off);
      if (lane >= off) x += t;
    }
    if (lane == 63) wsum[wv] = x;
    __syncthreads();
    if (wv == 0 && lane < 16) {
      int s2 = wsum[lane];
      #pragma unroll
      for (int off = 1; off < 16; off <<= 1) {
        int t = __shfl_up(s2, off);
        if (lane >= off) s2 += t;
      }
      wsum[lane] = s2;
    }
    __syncthreads();
    int carry = carry_s;
    int waveoff = wv ? wsum[wv - 1] : 0;
    int excl = carry + waveoff + (x - v);
    if (i < N) { offsets[i] = excl; cursor[i] = excl; }
    __syncthreads();
    if (tid == 0) carry_s = carry + wsum[15];
    __syncthreads();
  }
  if (tid == 0) offsets[N] = E;
}

// ---------------- scatter edges into CSR by dst ----------------------------
__global__ __launch_bounds__(256) void scatter_kernel(
    const int* __restrict__ src32, const int* __restrict__ dst32, int E,
    int* __restrict__ cursor, int* __restrict__ csr_src) {
  int e = blockIdx.x * 256 + threadIdx.x;
  if (e >= E) return;
  int pos = atomicAdd(&cursor[dst32[e]], 1);
  csr_src[pos] = src32[e];
}

// ---------------- H = X@W + b, fused row L2-norm ---------------------------
// 32 rows per block-iter staged transposed in LDS (stride 36: aligned float4
// reads, write conflicts capped at 8-way). W streamed from global (L1/L2 hot).
// Thread tile: 4 rows x 4 cols. 256 thr: wv=tid>>6 (4), rowgrp=(lane>>5),
// colgrp=lane&31 -> rows wv*8+rowgrp*4 .. +3, cols 4*colgrp .. +3.
__global__ __launch_bounds__(256) void gemm_norm_kernel(
    const float* __restrict__ X, const float* __restrict__ Wg,
    const float* __restrict__ bias, float* __restrict__ Hout,
    float* __restrict__ rnorm, int N) {
  __shared__ float xt[128][36];  // [k][row], 18KB
  int tid = threadIdx.x;
  int wv = tid >> 6, lane = tid & 63;
  int rowgrp = lane >> 5;
  int colgrp = lane & 31;
  int rbase = wv * 8 + rowgrp * 4;
  float4 bj = ((const float4*)bias)[colgrp];

  for (int r0 = blockIdx.x * 32; r0 < N; r0 += gridDim.x * 32) {
    __syncthreads();
    for (int idx = tid; idx < 32 * 128; idx += 256) {
      int rr = idx >> 7, cc = idx & 127;
      int r = r0 + rr; if (r >= N) r = N - 1;
      xt[cc][rr] = X[r * 128 + cc];
    }
    __syncthreads();
    float4 a0 = bj, a1 = bj, a2 = bj, a3 = bj;
    #pragma unroll 16
    for (int k = 0; k < 128; ++k) {
      float4 w = *(const float4*)(Wg + k * 128 + 4 * colgrp);
      float4 xv = *(const float4*)&xt[k][rbase];
      a0.x += xv.x * w.x; a0.y += xv.x * w.y; a0.z += xv.x * w.z; a0.w += xv.x * w.w;
      a1.x += xv.y * w.x; a1.y += xv.y * w.y; a1.z += xv.y * w.z; a1.w += xv.y * w.w;
      a2.x += xv.z * w.x; a2.y += xv.z * w.y; a2.z += xv.z * w.z; a2.w += xv.z * w.w;
      a3.x += xv.w * w.x; a3.y += xv.w * w.y; a3.z += xv.w * w.z; a3.w += xv.w * w.w;
    }
    float4 av[4] = {a0, a1, a2, a3};
    #pragma unroll
    for (int rr = 0; rr < 4; ++rr) {
      float4 aa = av[rr];
      float s = aa.x*aa.x + aa.y*aa.y + aa.z*aa.z + aa.w*aa.w;
      #pragma unroll
      for (int m = 16; m; m >>= 1) s += __shfl_xor(s, m);  // reduce 32-lane group
      int r = r0 + rbase + rr;
      if (r < N) {
        ((float4*)(Hout + r * 128))[colgrp] = aa;
        if (colgrp == 0) rnorm[r] = rsqrtf(s + 1e-12f);
      }
    }
  }
}

// ---------------- fused attention softmax + aggregate + relu ---------------
// One 64-lane wave per dst node; lane holds dims {2l, 2l+1}.
// score = beta * rnorm[d] * rnorm[s] * (h_d . h_s); softmax needs no max
// subtraction (|score| <= |beta|, shift-invariant).
__global__ __launch_bounds__(256) void agg_kernel(
    const float* __restrict__ Hm, const float* __restrict__ rnorm,
    const float* __restrict__ beta_p, const int* __restrict__ offsets,
    const int* __restrict__ csr_src, float* __restrict__ Y, int N) {
  int wid = (blockIdx.x * 256 + threadIdx.x) >> 6;
  int lane = threadIdx.x & 63;
  if (wid >= N) return;
  const float2* Hv = (const float2*)Hm;
  float2 hd = Hv[wid * 64 + lane];
  float rdb = rnorm[wid] * beta_p[0];
  int e0 = offsets[wid], e1 = offsets[wid + 1];
  float denom = 0.f, acc0 = 0.f, acc1 = 0.f;
  for (int e = e0; e < e1; ++e) {
    int s = csr_src[e];
    float2 hs = Hv[s * 64 + lane];
    float p = hd.x * hs.x + hd.y * hs.y;
    #pragma unroll
    for (int m = 32; m; m >>= 1) p += __shfl_xor(p, m);
    float w = __expf(p * rdb * rnorm[s]);
    denom += w;
    acc0 += w * hs.x; acc1 += w * hs.y;
  }
  float inv = 1.0f / denom;  // denom > 0 guaranteed by self-loop
  float o0 = acc0 * inv, o1 = acc1 * inv;
  float2 o;
  o.x = o0 > 0.f ? o0 : 0.f;
  o.y = o1 > 0.f ? o1 : 0.f;
  ((float2*)Y)[wid * 64 + lane] = o;
}

// ---------------- launcher -------------------------------------------------
extern "C" void kernel_launch(void* const* d_in, const int* in_sizes, int n_in,
                              void* d_out, int out_size, void* d_ws, size_t ws_size,
                              hipStream_t stream) {
  const float* x     = (const float*)d_in[0];
  const void*  ei    = d_in[1];
  const float* W1    = (const float*)d_in[2];
  const float* b1    = (const float*)d_in[3];
  const float* beta1 = (const float*)d_in[4];
  const float* W2    = (const float*)d_in[5];
  const float* b2    = (const float*)d_in[6];
  const float* beta2 = (const float*)d_in[7];
  float* out = (float*)d_out;

  int N = in_sizes[0] / FDIM;
  int E = in_sizes[1] / 2;

  char* p = (char*)d_ws;
  auto alloc = [&](size_t bytes) {
    char* r = p; p += (bytes + 255) & ~size_t(255); return r;
  };
  int*   flag    = (int*)alloc(4);
  int*   counts  = (int*)alloc(sizeof(int) * N);
  int*   offsets = (int*)alloc(sizeof(int) * (N + 1));
  int*   cursor  = (int*)alloc(sizeof(int) * N);
  int*   src32   = (int*)alloc(sizeof(int) * E);
  int*   dst32   = (int*)alloc(sizeof(int) * E);
  int*   csr     = (int*)alloc(sizeof(int) * E);
  float* h       = (float*)alloc(sizeof(float) * (size_t)N * FDIM);
  float* rn      = (float*)alloc(sizeof(float) * N);
  float* y1      = (float*)alloc(sizeof(float) * (size_t)N * FDIM);

  hipMemsetAsync(counts, 0, sizeof(int) * N, stream);
  detect_kernel<<<1, 64, 0, stream>>>((const int*)ei, flag);
  int cb = (E + 255) / 256;
  convert_count_kernel<<<cb, 256, 0, stream>>>(ei, flag, E, src32, dst32, counts);
  scan_kernel<<<1, 1024, 0, stream>>>(counts, offsets, cursor, N, E);
  scatter_kernel<<<cb, 256, 0, stream>>>(src32, dst32, E, cursor, csr);

  int ab = (N + 3) / 4;  // 4 waves (dst nodes) per 256-thread block
  gemm_norm_kernel<<<1024, 256, 0, stream>>>(x, W1, b1, h, rn, N);
  agg_kernel<<<ab, 256, 0, stream>>>(h, rn, beta1, offsets, csr, y1, N);
  gemm_norm_kernel<<<1024, 256, 0, stream>>>(y1, W2, b2, h, rn, N);
  agg_kernel<<<ab, 256, 0, stream>>>(h, rn, beta2, offsets, csr, out, N);
}

// Round 2
// 409.636 us; speedup vs baseline: 1.2968x; 1.2968x over previous
//
#include <hip/hip_runtime.h>
#include <hip/hip_bf16.h>

// AGNN 2-layer encoder: N=50000 nodes, E=850000 edges (w/ self-loops), D=H=128.
// Pipeline: detect edge dtype -> build CSR (by dst) once ->
//   [gemm+rownorm -> fused attn-aggregate(+relu)] x 2 layers.

#define FDIM 128

// ---------------- edge dtype probe: int64 => odd 32-bit words are all 0 ----
// Wave-parallel: lane i<32 checks word 2i+1 of the first 32 edge entries.
__global__ void detect_kernel(const int* __restrict__ ei, int* __restrict__ flag) {
  int lane = threadIdx.x & 63;
  int ok = 1;
  if (lane < 32) ok = (ei[2 * lane + 1] == 0);
  unsigned long long b = __ballot(ok);
  if (lane == 0) *flag = (b == ~0ull) ? 1 : 0;
}

// ---------------- normalize edges to int32 + per-dst histogram -------------
__global__ __launch_bounds__(256) void convert_count_kernel(
    const void* __restrict__ ei, const int* __restrict__ flag, int E,
    int* __restrict__ src32, int* __restrict__ dst32, int* __restrict__ counts) {
  int e = blockIdx.x * 256 + threadIdx.x;
  if (e >= E) return;
  int s, d;
  if (*flag) {
    const long long* p = (const long long*)ei;
    s = (int)p[e]; d = (int)p[E + e];
  } else {
    const int* p = (const int*)ei;
    s = p[e]; d = p[E + e];
  }
  src32[e] = s; dst32[e] = d;
  atomicAdd(&counts[d], 1);
}

// ---------------- single-block exclusive scan, 8 elements/thread -----------
__global__ __launch_bounds__(1024) void scan_kernel(
    const int* __restrict__ counts, int* __restrict__ offsets,
    int* __restrict__ cursor, int N, int E) {
  __shared__ int wsum[16];
  __shared__ int carry_s;
  int tid = threadIdx.x, lane = tid & 63, wv = tid >> 6;
  if (tid == 0) carry_s = 0;
  __syncthreads();
  for (int base = 0; base < N; base += 8192) {
    int i0 = base + tid * 8;
    int v[8];
    if (i0 + 7 < N) {
      int4 a = *(const int4*)(counts + i0);
      int4 b = *(const int4*)(counts + i0 + 4);
      v[0]=a.x; v[1]=a.y; v[2]=a.z; v[3]=a.w;
      v[4]=b.x; v[5]=b.y; v[6]=b.z; v[7]=b.w;
    } else {
      #pragma unroll
      for (int j = 0; j < 8; ++j) v[j] = (i0 + j < N) ? counts[i0 + j] : 0;
    }
    int pre[8], t = 0;
    #pragma unroll
    for (int j = 0; j < 8; ++j) { pre[j] = t; t += v[j]; }
    int x = t;
    #pragma unroll
    for (int off = 1; off < 64; off <<= 1) {
      int u = __shfl_up(x, off);
      if (lane >= off) x += u;
    }
    if (lane == 63) wsum[wv] = x;
    __syncthreads();
    if (wv == 0 && lane < 16) {
      int s2 = wsum[lane];
      #pragma unroll
      for (int off = 1; off < 16; off <<= 1) {
        int u = __shfl_up(s2, off);
        if (lane >= off) s2 += u;
      }
      wsum[lane] = s2;
    }
    __syncthreads();
    int carry = carry_s;
    int waveoff = wv ? wsum[wv - 1] : 0;
    int ebase = carry + waveoff + (x - t);
    #pragma unroll
    for (int j = 0; j < 8; ++j) {
      int i = i0 + j;
      if (i < N) { offsets[i] = ebase + pre[j]; cursor[i] = ebase + pre[j]; }
    }
    __syncthreads();
    if (tid == 0) carry_s = carry + wsum[15];
    __syncthreads();
  }
  if (tid == 0) offsets[N] = E;
}

// ---------------- scatter edges into CSR by dst ----------------------------
__global__ __launch_bounds__(256) void scatter_kernel(
    const int* __restrict__ src32, const int* __restrict__ dst32, int E,
    int* __restrict__ cursor, int* __restrict__ csr_src) {
  int e = blockIdx.x * 256 + threadIdx.x;
  if (e >= E) return;
  int pos = atomicAdd(&cursor[dst32[e]], 1);
  csr_src[pos] = src32[e];
}

// ---------------- H = X@W + b, fused row L2-norm ---------------------------
// 64-row tile per block. X staged transposed in LDS (stride 72: float4-aligned
// reads, broadcast across 32-lane col groups = conflict-free; scalar staging
// writes are 8-way but only 64 instrs/thread vs 4096 FMA -> negligible).
// Thread tile: 8 rows x 4 cols. wv=tid>>6, rowgrp=(lane>>5), colgrp=lane&31
// -> rows wv*16+rowgrp*8 .. +7, cols 4*colgrp .. +3.
__global__ __launch_bounds__(256) void gemm_norm_kernel(
    const float* __restrict__ X, const float* __restrict__ Wg,
    const float* __restrict__ bias, float* __restrict__ Hout,
    float* __restrict__ rnorm, int N) {
  __shared__ float xt[128][72];  // [k][row], 36.9KB
  int tid = threadIdx.x;
  int wv = tid >> 6, lane = tid & 63;
  int rowgrp = lane >> 5;
  int colgrp = lane & 31;
  int rbase = wv * 16 + rowgrp * 8;
  float4 bj = ((const float4*)bias)[colgrp];
  int r0 = blockIdx.x * 64;

  for (int idx = tid; idx < 64 * 128; idx += 256) {
    int rr = idx >> 7, cc = idx & 127;
    int r = r0 + rr; if (r >= N) r = N - 1;
    xt[cc][rr] = X[r * 128 + cc];
  }
  __syncthreads();

  float4 a[8];
  #pragma unroll
  for (int rr = 0; rr < 8; ++rr) a[rr] = bj;

  #pragma unroll 4
  for (int k = 0; k < 128; ++k) {
    float4 w = *(const float4*)(Wg + k * 128 + 4 * colgrp);
    float4 xv0 = *(const float4*)&xt[k][rbase];
    float4 xv1 = *(const float4*)&xt[k][rbase + 4];
    a[0].x += xv0.x*w.x; a[0].y += xv0.x*w.y; a[0].z += xv0.x*w.z; a[0].w += xv0.x*w.w;
    a[1].x += xv0.y*w.x; a[1].y += xv0.y*w.y; a[1].z += xv0.y*w.z; a[1].w += xv0.y*w.w;
    a[2].x += xv0.z*w.x; a[2].y += xv0.z*w.y; a[2].z += xv0.z*w.z; a[2].w += xv0.z*w.w;
    a[3].x += xv0.w*w.x; a[3].y += xv0.w*w.y; a[3].z += xv0.w*w.z; a[3].w += xv0.w*w.w;
    a[4].x += xv1.x*w.x; a[4].y += xv1.x*w.y; a[4].z += xv1.x*w.z; a[4].w += xv1.x*w.w;
    a[5].x += xv1.y*w.x; a[5].y += xv1.y*w.y; a[5].z += xv1.y*w.z; a[5].w += xv1.y*w.w;
    a[6].x += xv1.z*w.x; a[6].y += xv1.z*w.y; a[6].z += xv1.z*w.z; a[6].w += xv1.z*w.w;
    a[7].x += xv1.w*w.x; a[7].y += xv1.w*w.y; a[7].z += xv1.w*w.z; a[7].w += xv1.w*w.w;
  }

  #pragma unroll
  for (int rr = 0; rr < 8; ++rr) {
    float4 aa = a[rr];
    float s = aa.x*aa.x + aa.y*aa.y + aa.z*aa.z + aa.w*aa.w;
    #pragma unroll
    for (int m = 16; m; m >>= 1) s += __shfl_xor(s, m);  // 32-lane col group
    int r = r0 + rbase + rr;
    if (r < N) {
      ((float4*)(Hout + r * 128))[colgrp] = aa;
      if (colgrp == 0) rnorm[r] = rsqrtf(s + 1e-12f);
    }
  }
}

// ---------------- fused attention softmax + aggregate + relu ---------------
// One 64-lane wave per dst node, split into 4 groups of 16 lanes; each group
// scores/accumulates a different edge (4 gather chains in flight). Sublane l
// holds dims {4l..4l+3} and {64+4l..64+4l+3} (two coalesced float4 gathers).
// score = beta * rnorm[d] * rnorm[s] * (h_d . h_s); |score|<=|beta| so the
// softmax needs no max subtraction (shift-invariant).
__global__ __launch_bounds__(256) void agg_kernel(
    const float* __restrict__ Hm, const float* __restrict__ rnorm,
    const float* __restrict__ beta_p, const int* __restrict__ offsets,
    const int* __restrict__ csr_src, float* __restrict__ Y, int N) {
  int wid = (blockIdx.x * 256 + threadIdx.x) >> 6;
  int lane = threadIdx.x & 63;
  if (wid >= N) return;
  int g = lane >> 4;   // edge group 0..3
  int l = lane & 15;   // dim sublane
  const float4* H4 = (const float4*)Hm;
  float4 hd0 = H4[wid * 32 + l];
  float4 hd1 = H4[wid * 32 + 16 + l];
  float rdb = rnorm[wid] * beta_p[0];
  int e0 = offsets[wid], e1 = offsets[wid + 1];
  float denom = 0.f;
  float4 acc0 = {0.f,0.f,0.f,0.f}, acc1 = {0.f,0.f,0.f,0.f};

  for (int eb = e0; eb < e1; eb += 4) {
    int e = eb + g;
    bool valid = e < e1;
    int s = valid ? csr_src[e] : wid;
    float rs = rnorm[s];
    float4 hs0 = H4[s * 32 + l];
    float4 hs1 = H4[s * 32 + 16 + l];
    float p = hs0.x*hd0.x + hs0.y*hd0.y + hs0.z*hd0.z + hs0.w*hd0.w
            + hs1.x*hd1.x + hs1.y*hd1.y + hs1.z*hd1.z + hs1.w*hd1.w;
    p += __shfl_xor(p, 1);
    p += __shfl_xor(p, 2);
    p += __shfl_xor(p, 4);
    p += __shfl_xor(p, 8);
    float w = valid ? __expf(p * rdb * rs) : 0.f;
    denom += w;
    acc0.x += w*hs0.x; acc0.y += w*hs0.y; acc0.z += w*hs0.z; acc0.w += w*hs0.w;
    acc1.x += w*hs1.x; acc1.y += w*hs1.y; acc1.z += w*hs1.z; acc1.w += w*hs1.w;
  }

  // cross-group reduction (xor 16, 32)
  #pragma unroll
  for (int m = 16; m <= 32; m <<= 1) {
    denom  += __shfl_xor(denom,  m);
    acc0.x += __shfl_xor(acc0.x, m); acc0.y += __shfl_xor(acc0.y, m);
    acc0.z += __shfl_xor(acc0.z, m); acc0.w += __shfl_xor(acc0.w, m);
    acc1.x += __shfl_xor(acc1.x, m); acc1.y += __shfl_xor(acc1.y, m);
    acc1.z += __shfl_xor(acc1.z, m); acc1.w += __shfl_xor(acc1.w, m);
  }
  if (g == 0) {
    float inv = 1.0f / denom;  // denom > 0 guaranteed by self-loop
    float4 o0, o1;
    o0.x = fmaxf(acc0.x*inv, 0.f); o0.y = fmaxf(acc0.y*inv, 0.f);
    o0.z = fmaxf(acc0.z*inv, 0.f); o0.w = fmaxf(acc0.w*inv, 0.f);
    o1.x = fmaxf(acc1.x*inv, 0.f); o1.y = fmaxf(acc1.y*inv, 0.f);
    o1.z = fmaxf(acc1.z*inv, 0.f); o1.w = fmaxf(acc1.w*inv, 0.f);
    ((float4*)Y)[wid * 32 + l] = o0;
    ((float4*)Y)[wid * 32 + 16 + l] = o1;
  }
}

// ---------------- launcher -------------------------------------------------
extern "C" void kernel_launch(void* const* d_in, const int* in_sizes, int n_in,
                              void* d_out, int out_size, void* d_ws, size_t ws_size,
                              hipStream_t stream) {
  const float* x     = (const float*)d_in[0];
  const void*  ei    = d_in[1];
  const float* W1    = (const float*)d_in[2];
  const float* b1    = (const float*)d_in[3];
  const float* beta1 = (const float*)d_in[4];
  const float* W2    = (const float*)d_in[5];
  const float* b2    = (const float*)d_in[6];
  const float* beta2 = (const float*)d_in[7];
  float* out = (float*)d_out;

  int N = in_sizes[0] / FDIM;
  int E = in_sizes[1] / 2;

  char* p = (char*)d_ws;
  auto alloc = [&](size_t bytes) {
    char* r = p; p += (bytes + 255) & ~size_t(255); return r;
  };
  int*   flag    = (int*)alloc(4);
  int*   counts  = (int*)alloc(sizeof(int) * N);
  int*   offsets = (int*)alloc(sizeof(int) * (N + 1));
  int*   cursor  = (int*)alloc(sizeof(int) * N);
  int*   src32   = (int*)alloc(sizeof(int) * E);
  int*   dst32   = (int*)alloc(sizeof(int) * E);
  int*   csr     = (int*)alloc(sizeof(int) * E);
  float* h       = (float*)alloc(sizeof(float) * (size_t)N * FDIM);
  float* rn      = (float*)alloc(sizeof(float) * N);
  float* y1      = (float*)alloc(sizeof(float) * (size_t)N * FDIM);

  hipMemsetAsync(counts, 0, sizeof(int) * N, stream);
  detect_kernel<<<1, 64, 0, stream>>>((const int*)ei, flag);
  int cb = (E + 255) / 256;
  convert_count_kernel<<<cb, 256, 0, stream>>>(ei, flag, E, src32, dst32, counts);
  scan_kernel<<<1, 1024, 0, stream>>>(counts, offsets, cursor, N, E);
  scatter_kernel<<<cb, 256, 0, stream>>>(src32, dst32, E, cursor, csr);

  int gb = (N + 63) / 64;
  int ab = (N + 3) / 4;  // 4 waves (dst nodes) per 256-thread block
  gemm_norm_kernel<<<gb, 256, 0, stream>>>(x, W1, b1, h, rn, N);
  agg_kernel<<<ab, 256, 0, stream>>>(h, rn, beta1, offsets, csr, y1, N);
  gemm_norm_kernel<<<gb, 256, 0, stream>>>(y1, W2, b2, h, rn, N);
  agg_kernel<<<ab, 256, 0, stream>>>(h, rn, beta2, offsets, csr, out, N);
}

// Round 3
// 362.033 us; speedup vs baseline: 1.4673x; 1.1315x over previous
//
#include <hip/hip_runtime.h>
#include <hip/hip_bf16.h>
#include <hip/hip_fp16.h>

// AGNN 2-layer encoder: N=50000 nodes, E=850000 edges (w/ self-loops), D=H=128.
// Pipeline: detect edge dtype -> build CSR (by dst) once ->
//   [gemm+rownorm (fp16 H out) -> fused attn-aggregate(+relu, f32 out)] x 2.
// H stored fp16: halves gather traffic + footprint; adds ~1e-3 abs error
// (threshold 1.375e-2, prior margin 7x).

#define FDIM 128

// ---------------- edge dtype probe: int64 => odd 32-bit words are all 0 ----
__global__ void detect_kernel(const int* __restrict__ ei, int* __restrict__ flag) {
  int lane = threadIdx.x & 63;
  int ok = 1;
  if (lane < 32) ok = (ei[2 * lane + 1] == 0);
  unsigned long long b = __ballot(ok);
  if (lane == 0) *flag = (b == ~0ull) ? 1 : 0;
}

// ---------------- normalize edges to int32 + per-dst histogram -------------
__global__ __launch_bounds__(256) void convert_count_kernel(
    const void* __restrict__ ei, const int* __restrict__ flag, int E,
    int* __restrict__ src32, int* __restrict__ dst32, int* __restrict__ counts) {
  int e = blockIdx.x * 256 + threadIdx.x;
  if (e >= E) return;
  int s, d;
  if (*flag) {
    const long long* p = (const long long*)ei;
    s = (int)p[e]; d = (int)p[E + e];
  } else {
    const int* p = (const int*)ei;
    s = p[e]; d = p[E + e];
  }
  src32[e] = s; dst32[e] = d;
  atomicAdd(&counts[d], 1);
}

// ---------------- single-block exclusive scan, 8 elements/thread -----------
__global__ __launch_bounds__(1024) void scan_kernel(
    const int* __restrict__ counts, int* __restrict__ offsets,
    int* __restrict__ cursor, int N, int E) {
  __shared__ int wsum[16];
  __shared__ int carry_s;
  int tid = threadIdx.x, lane = tid & 63, wv = tid >> 6;
  if (tid == 0) carry_s = 0;
  __syncthreads();
  for (int base = 0; base < N; base += 8192) {
    int i0 = base + tid * 8;
    int v[8];
    if (i0 + 7 < N) {
      int4 a = *(const int4*)(counts + i0);
      int4 b = *(const int4*)(counts + i0 + 4);
      v[0]=a.x; v[1]=a.y; v[2]=a.z; v[3]=a.w;
      v[4]=b.x; v[5]=b.y; v[6]=b.z; v[7]=b.w;
    } else {
      #pragma unroll
      for (int j = 0; j < 8; ++j) v[j] = (i0 + j < N) ? counts[i0 + j] : 0;
    }
    int pre[8], t = 0;
    #pragma unroll
    for (int j = 0; j < 8; ++j) { pre[j] = t; t += v[j]; }
    int x = t;
    #pragma unroll
    for (int off = 1; off < 64; off <<= 1) {
      int u = __shfl_up(x, off);
      if (lane >= off) x += u;
    }
    if (lane == 63) wsum[wv] = x;
    __syncthreads();
    if (wv == 0 && lane < 16) {
      int s2 = wsum[lane];
      #pragma unroll
      for (int off = 1; off < 16; off <<= 1) {
        int u = __shfl_up(s2, off);
        if (lane >= off) s2 += u;
      }
      wsum[lane] = s2;
    }
    __syncthreads();
    int carry = carry_s;
    int waveoff = wv ? wsum[wv - 1] : 0;
    int ebase = carry + waveoff + (x - t);
    #pragma unroll
    for (int j = 0; j < 8; ++j) {
      int i = i0 + j;
      if (i < N) { offsets[i] = ebase + pre[j]; cursor[i] = ebase + pre[j]; }
    }
    __syncthreads();
    if (tid == 0) carry_s = carry + wsum[15];
    __syncthreads();
  }
  if (tid == 0) offsets[N] = E;
}

// ---------------- scatter edges into CSR by dst ----------------------------
__global__ __launch_bounds__(256) void scatter_kernel(
    const int* __restrict__ src32, const int* __restrict__ dst32, int E,
    int* __restrict__ cursor, int* __restrict__ csr_src) {
  int e = blockIdx.x * 256 + threadIdx.x;
  if (e >= E) return;
  int pos = atomicAdd(&cursor[dst32[e]], 1);
  csr_src[pos] = src32[e];
}

// ---------------- H = X@W + b, fused row L2-norm, fp16 output --------------
// 64-row tile per block. X staged transposed in LDS (stride 72). Thread tile:
// 8 rows x 4 cols. Accumulate f32, emit fp16 H + f32 rnorm.
__global__ __launch_bounds__(256) void gemm_norm_kernel(
    const float* __restrict__ X, const float* __restrict__ Wg,
    const float* __restrict__ bias, __half* __restrict__ H16,
    float* __restrict__ rnorm, int N) {
  __shared__ float xt[128][72];  // [k][row], 36.9KB
  int tid = threadIdx.x;
  int wv = tid >> 6, lane = tid & 63;
  int rowgrp = lane >> 5;
  int colgrp = lane & 31;
  int rbase = wv * 16 + rowgrp * 8;
  float4 bj = ((const float4*)bias)[colgrp];
  int r0 = blockIdx.x * 64;

  for (int idx = tid; idx < 64 * 128; idx += 256) {
    int rr = idx >> 7, cc = idx & 127;
    int r = r0 + rr; if (r >= N) r = N - 1;
    xt[cc][rr] = X[r * 128 + cc];
  }
  __syncthreads();

  float4 a[8];
  #pragma unroll
  for (int rr = 0; rr < 8; ++rr) a[rr] = bj;

  #pragma unroll 4
  for (int k = 0; k < 128; ++k) {
    float4 w = *(const float4*)(Wg + k * 128 + 4 * colgrp);
    float4 xv0 = *(const float4*)&xt[k][rbase];
    float4 xv1 = *(const float4*)&xt[k][rbase + 4];
    a[0].x += xv0.x*w.x; a[0].y += xv0.x*w.y; a[0].z += xv0.x*w.z; a[0].w += xv0.x*w.w;
    a[1].x += xv0.y*w.x; a[1].y += xv0.y*w.y; a[1].z += xv0.y*w.z; a[1].w += xv0.y*w.w;
    a[2].x += xv0.z*w.x; a[2].y += xv0.z*w.y; a[2].z += xv0.z*w.z; a[2].w += xv0.z*w.w;
    a[3].x += xv0.w*w.x; a[3].y += xv0.w*w.y; a[3].z += xv0.w*w.z; a[3].w += xv0.w*w.w;
    a[4].x += xv1.x*w.x; a[4].y += xv1.x*w.y; a[4].z += xv1.x*w.z; a[4].w += xv1.x*w.w;
    a[5].x += xv1.y*w.x; a[5].y += xv1.y*w.y; a[5].z += xv1.y*w.z; a[5].w += xv1.y*w.w;
    a[6].x += xv1.z*w.x; a[6].y += xv1.z*w.y; a[6].z += xv1.z*w.z; a[6].w += xv1.z*w.w;
    a[7].x += xv1.w*w.x; a[7].y += xv1.w*w.y; a[7].z += xv1.w*w.z; a[7].w += xv1.w*w.w;
  }

  #pragma unroll
  for (int rr = 0; rr < 8; ++rr) {
    float4 aa = a[rr];
    float s = aa.x*aa.x + aa.y*aa.y + aa.z*aa.z + aa.w*aa.w;
    #pragma unroll
    for (int m = 16; m; m >>= 1) s += __shfl_xor(s, m);  // 32-lane col group
    int r = r0 + rbase + rr;
    if (r < N) {
      __half2 lo = __floats2half2_rn(aa.x, aa.y);
      __half2 hi = __floats2half2_rn(aa.z, aa.w);
      __half2* dst = (__half2*)(H16 + (size_t)r * 128 + 4 * colgrp);
      dst[0] = lo; dst[1] = hi;
      if (colgrp == 0) rnorm[r] = rsqrtf(s + 1e-12f);
    }
  }
}

// ---------------- fused attention softmax + aggregate + relu ---------------
// One wave per dst node, 4 groups x 16 lanes; each group scores a different
// edge. Sublane l holds dims 8l..8l+7 (ONE 16B fp16 gather per edge-lane).
// Explicit 1-deep prefetch pipeline hides gather latency under scoring.
// score = beta * rnorm[d] * rnorm[s] * (h_d . h_s); |score|<=|beta| so no
// max-subtraction needed (softmax shift-invariant).
__global__ __launch_bounds__(256) void agg_kernel(
    const __half* __restrict__ H16, const float* __restrict__ rnorm,
    const float* __restrict__ beta_p, const int* __restrict__ offsets,
    const int* __restrict__ csr_src, float* __restrict__ Y, int N) {
  int wid = (blockIdx.x * 256 + threadIdx.x) >> 6;
  int lane = threadIdx.x & 63;
  if (wid >= N) return;
  int g = lane >> 4;   // edge group 0..3
  int l = lane & 15;   // dim sublane: dims 8l..8l+7
  const float4* H4 = (const float4*)H16;  // 16B = 8 halves

  // own (dst) fragment -> 8 floats
  float4 hdv = H4[(size_t)wid * 16 + l];
  const __half2* hdp = (const __half2*)&hdv;
  float2 d0 = __half22float2(hdp[0]);
  float2 d1 = __half22float2(hdp[1]);
  float2 d2 = __half22float2(hdp[2]);
  float2 d3 = __half22float2(hdp[3]);
  float rdb = rnorm[wid] * beta_p[0];

  int e0 = offsets[wid], e1 = offsets[wid + 1];
  float denom = 0.f;
  float acc[8] = {0.f,0.f,0.f,0.f,0.f,0.f,0.f,0.f};

  // prefetch pipeline stage 0
  int e = e0 + g;
  bool valid = e < e1;
  int s = valid ? csr_src[e] : wid;
  float4 hv = H4[(size_t)s * 16 + l];
  float rs = rnorm[s];

  for (int eb = e0; eb < e1; eb += 4) {
    // issue next stage's loads (independent of current compute)
    int en = e + 4;
    bool vn = en < e1;
    int sn = vn ? csr_src[en] : wid;
    float4 hvn = H4[(size_t)sn * 16 + l];
    float rsn = rnorm[sn];

    // score + accumulate current
    const __half2* hp = (const __half2*)&hv;
    float2 q0 = __half22float2(hp[0]);
    float2 q1 = __half22float2(hp[1]);
    float2 q2 = __half22float2(hp[2]);
    float2 q3 = __half22float2(hp[3]);
    float p = q0.x*d0.x + q0.y*d0.y + q1.x*d1.x + q1.y*d1.y
            + q2.x*d2.x + q2.y*d2.y + q3.x*d3.x + q3.y*d3.y;
    p += __shfl_xor(p, 1);
    p += __shfl_xor(p, 2);
    p += __shfl_xor(p, 4);
    p += __shfl_xor(p, 8);
    float w = valid ? __expf(p * rdb * rs) : 0.f;
    denom += w;
    acc[0] += w*q0.x; acc[1] += w*q0.y; acc[2] += w*q1.x; acc[3] += w*q1.y;
    acc[4] += w*q2.x; acc[5] += w*q2.y; acc[6] += w*q3.x; acc[7] += w*q3.y;

    // rotate pipeline
    e = en; valid = vn; s = sn; hv = hvn; rs = rsn;
  }

  // cross-group reduction (xor 16, 32)
  #pragma unroll
  for (int m = 16; m <= 32; m <<= 1) {
    denom += __shfl_xor(denom, m);
    #pragma unroll
    for (int j = 0; j < 8; ++j) acc[j] += __shfl_xor(acc[j], m);
  }
  if (g == 0) {
    float inv = 1.0f / denom;  // denom > 0 guaranteed by self-loop
    float4 o0, o1;
    o0.x = fmaxf(acc[0]*inv, 0.f); o0.y = fmaxf(acc[1]*inv, 0.f);
    o0.z = fmaxf(acc[2]*inv, 0.f); o0.w = fmaxf(acc[3]*inv, 0.f);
    o1.x = fmaxf(acc[4]*inv, 0.f); o1.y = fmaxf(acc[5]*inv, 0.f);
    o1.z = fmaxf(acc[6]*inv, 0.f); o1.w = fmaxf(acc[7]*inv, 0.f);
    ((float4*)Y)[(size_t)wid * 32 + 2 * l] = o0;
    ((float4*)Y)[(size_t)wid * 32 + 2 * l + 1] = o1;
  }
}

// ---------------- launcher -------------------------------------------------
extern "C" void kernel_launch(void* const* d_in, const int* in_sizes, int n_in,
                              void* d_out, int out_size, void* d_ws, size_t ws_size,
                              hipStream_t stream) {
  const float* x     = (const float*)d_in[0];
  const void*  ei    = d_in[1];
  const float* W1    = (const float*)d_in[2];
  const float* b1    = (const float*)d_in[3];
  const float* beta1 = (const float*)d_in[4];
  const float* W2    = (const float*)d_in[5];
  const float* b2    = (const float*)d_in[6];
  const float* beta2 = (const float*)d_in[7];
  float* out = (float*)d_out;

  int N = in_sizes[0] / FDIM;
  int E = in_sizes[1] / 2;

  char* p = (char*)d_ws;
  auto alloc = [&](size_t bytes) {
    char* r = p; p += (bytes + 255) & ~size_t(255); return r;
  };
  int*    flag    = (int*)alloc(4);
  int*    counts  = (int*)alloc(sizeof(int) * N);
  int*    offsets = (int*)alloc(sizeof(int) * (N + 1));
  int*    cursor  = (int*)alloc(sizeof(int) * N);
  int*    src32   = (int*)alloc(sizeof(int) * E);
  int*    dst32   = (int*)alloc(sizeof(int) * E);
  int*    csr     = (int*)alloc(sizeof(int) * E);
  __half* h16     = (__half*)alloc(sizeof(__half) * (size_t)N * FDIM);
  float*  rn      = (float*)alloc(sizeof(float) * N);
  float*  y1      = (float*)alloc(sizeof(float) * (size_t)N * FDIM);

  hipMemsetAsync(counts, 0, sizeof(int) * N, stream);
  detect_kernel<<<1, 64, 0, stream>>>((const int*)ei, flag);
  int cb = (E + 255) / 256;
  convert_count_kernel<<<cb, 256, 0, stream>>>(ei, flag, E, src32, dst32, counts);
  scan_kernel<<<1, 1024, 0, stream>>>(counts, offsets, cursor, N, E);
  scatter_kernel<<<cb, 256, 0, stream>>>(src32, dst32, E, cursor, csr);

  int gb = (N + 63) / 64;
  int ab = (N + 3) / 4;  // 4 waves (dst nodes) per 256-thread block
  gemm_norm_kernel<<<gb, 256, 0, stream>>>(x, W1, b1, h16, rn, N);
  agg_kernel<<<ab, 256, 0, stream>>>(h16, rn, beta1, offsets, csr, y1, N);
  gemm_norm_kernel<<<gb, 256, 0, stream>>>(y1, W2, b2, h16, rn, N);
  agg_kernel<<<ab, 256, 0, stream>>>(h16, rn, beta2, offsets, csr, out, N);
}

// Round 4
// 275.716 us; speedup vs baseline: 1.9267x; 1.3131x over previous
//
#include <hip/hip_runtime.h>
#include <hip/hip_bf16.h>
#include <hip/hip_fp16.h>

// AGNN 2-layer encoder: N=50000 nodes, E=850000 edges (w/ self-loops), D=H=128.
// Pipeline: convert(+dtype-detect,+histogram,+rank) -> hierarchical scan ->
//   atomic-free scatter -> [gemm+rownorm (fp16 H) -> fused attn-agg(+relu)] x2.

#define FDIM 128
#define SCAN_CHUNK 2048  // 256 threads x 8 elems

// ------- convert edges to int32 + per-dst histogram + within-dst rank ------
// dtype detect fused: int64 <=> odd 32-bit words of first 32 entries all 0.
__global__ __launch_bounds__(256) void convert_count_kernel(
    const void* __restrict__ ei, int E,
    int* __restrict__ src32, int* __restrict__ dst32,
    int* __restrict__ rank, int* __restrict__ counts) {
  const int* eii = (const int*)ei;
  int lane = threadIdx.x & 63;
  int ok = (lane < 32) ? (eii[2 * lane + 1] == 0) : 1;
  bool is64 = (__ballot(ok) == ~0ull);

  int e = blockIdx.x * 256 + threadIdx.x;
  if (e >= E) return;
  int s, d;
  if (is64) {
    const long long* p = (const long long*)ei;
    s = (int)p[e]; d = (int)p[E + e];
  } else {
    s = eii[e]; d = eii[E + e];
  }
  src32[e] = s; dst32[e] = d;
  rank[e] = atomicAdd(&counts[d], 1);  // old value = within-dst slot
}

// ------- scan stage A: per-block (2048-elem chunk) sums --------------------
__global__ __launch_bounds__(256) void scan_a_kernel(
    const int* __restrict__ counts, int* __restrict__ bsum, int N) {
  __shared__ int ws[4];
  int tid = threadIdx.x;
  int i0 = blockIdx.x * SCAN_CHUNK + tid * 8;
  int s = 0;
  if (i0 + 7 < N) {
    int4 a = *(const int4*)(counts + i0);
    int4 b = *(const int4*)(counts + i0 + 4);
    s = a.x + a.y + a.z + a.w + b.x + b.y + b.z + b.w;
  } else {
    #pragma unroll
    for (int j = 0; j < 8; ++j) if (i0 + j < N) s += counts[i0 + j];
  }
  #pragma unroll
  for (int m = 32; m; m >>= 1) s += __shfl_xor(s, m);
  int lane = tid & 63, wv = tid >> 6;
  if (lane == 0) ws[wv] = s;
  __syncthreads();
  if (tid == 0) bsum[blockIdx.x] = ws[0] + ws[1] + ws[2] + ws[3];
}

// ------- scan stage C: per-block exclusive scan + cross-block base ---------
// Each block re-derives its base by summing bsum[0..blockIdx.x-1] (NB<=64ish,
// lanewise strided + wave reduce -> trivial).
__global__ __launch_bounds__(256) void scan_c_kernel(
    const int* __restrict__ counts, const int* __restrict__ bsum,
    int* __restrict__ offsets, int N, int E) {
  __shared__ int wsum[4];
  int tid = threadIdx.x, lane = tid & 63, wv = tid >> 6;

  int bse = 0;
  for (int j = lane; j < (int)blockIdx.x; j += 64) bse += bsum[j];
  #pragma unroll
  for (int m = 32; m; m >>= 1) bse += __shfl_xor(bse, m);

  int i0 = blockIdx.x * SCAN_CHUNK + tid * 8;
  int v[8];
  if (i0 + 7 < N) {
    int4 a = *(const int4*)(counts + i0);
    int4 b = *(const int4*)(counts + i0 + 4);
    v[0]=a.x; v[1]=a.y; v[2]=a.z; v[3]=a.w;
    v[4]=b.x; v[5]=b.y; v[6]=b.z; v[7]=b.w;
  } else {
    #pragma unroll
    for (int j = 0; j < 8; ++j) v[j] = (i0 + j < N) ? counts[i0 + j] : 0;
  }
  int pre[8], t = 0;
  #pragma unroll
  for (int j = 0; j < 8; ++j) { pre[j] = t; t += v[j]; }
  int x = t;
  #pragma unroll
  for (int off = 1; off < 64; off <<= 1) {
    int u = __shfl_up(x, off);
    if (lane >= off) x += u;
  }
  if (lane == 63) wsum[wv] = x;
  __syncthreads();
  int waveoff = 0;
  #pragma unroll
  for (int w = 0; w < 4; ++w) if (w < wv) waveoff += wsum[w];
  int ebase = bse + waveoff + (x - t);
  #pragma unroll
  for (int j = 0; j < 8; ++j) {
    int i = i0 + j;
    if (i < N) offsets[i] = ebase + pre[j];
  }
  if (blockIdx.x == 0 && tid == 0) offsets[N] = E;
}

// ------- atomic-free scatter: pos = offsets[dst] + rank --------------------
__global__ __launch_bounds__(256) void scatter_kernel(
    const int* __restrict__ src32, const int* __restrict__ dst32,
    const int* __restrict__ rank, const int* __restrict__ offsets, int E,
    int* __restrict__ csr_src) {
  int e = blockIdx.x * 256 + threadIdx.x;
  if (e >= E) return;
  csr_src[offsets[dst32[e]] + rank[e]] = src32[e];
}

// ---------------- H = X@W + b, fused row L2-norm, fp16 output --------------
__global__ __launch_bounds__(256) void gemm_norm_kernel(
    const float* __restrict__ X, const float* __restrict__ Wg,
    const float* __restrict__ bias, __half* __restrict__ H16,
    float* __restrict__ rnorm, int N) {
  __shared__ float xt[128][72];  // [k][row], 36.9KB
  int tid = threadIdx.x;
  int wv = tid >> 6, lane = tid & 63;
  int rowgrp = lane >> 5;
  int colgrp = lane & 31;
  int rbase = wv * 16 + rowgrp * 8;
  float4 bj = ((const float4*)bias)[colgrp];
  int r0 = blockIdx.x * 64;

  for (int idx = tid; idx < 64 * 128; idx += 256) {
    int rr = idx >> 7, cc = idx & 127;
    int r = r0 + rr; if (r >= N) r = N - 1;
    xt[cc][rr] = X[r * 128 + cc];
  }
  __syncthreads();

  float4 a[8];
  #pragma unroll
  for (int rr = 0; rr < 8; ++rr) a[rr] = bj;

  #pragma unroll 4
  for (int k = 0; k < 128; ++k) {
    float4 w = *(const float4*)(Wg + k * 128 + 4 * colgrp);
    float4 xv0 = *(const float4*)&xt[k][rbase];
    float4 xv1 = *(const float4*)&xt[k][rbase + 4];
    a[0].x += xv0.x*w.x; a[0].y += xv0.x*w.y; a[0].z += xv0.x*w.z; a[0].w += xv0.x*w.w;
    a[1].x += xv0.y*w.x; a[1].y += xv0.y*w.y; a[1].z += xv0.y*w.z; a[1].w += xv0.y*w.w;
    a[2].x += xv0.z*w.x; a[2].y += xv0.z*w.y; a[2].z += xv0.z*w.z; a[2].w += xv0.z*w.w;
    a[3].x += xv0.w*w.x; a[3].y += xv0.w*w.y; a[3].z += xv0.w*w.z; a[3].w += xv0.w*w.w;
    a[4].x += xv1.x*w.x; a[4].y += xv1.x*w.y; a[4].z += xv1.x*w.z; a[4].w += xv1.x*w.w;
    a[5].x += xv1.y*w.x; a[5].y += xv1.y*w.y; a[5].z += xv1.y*w.z; a[5].w += xv1.y*w.w;
    a[6].x += xv1.z*w.x; a[6].y += xv1.z*w.y; a[6].z += xv1.z*w.z; a[6].w += xv1.z*w.w;
    a[7].x += xv1.w*w.x; a[7].y += xv1.w*w.y; a[7].z += xv1.w*w.z; a[7].w += xv1.w*w.w;
  }

  #pragma unroll
  for (int rr = 0; rr < 8; ++rr) {
    float4 aa = a[rr];
    float s = aa.x*aa.x + aa.y*aa.y + aa.z*aa.z + aa.w*aa.w;
    #pragma unroll
    for (int m = 16; m; m >>= 1) s += __shfl_xor(s, m);  // 32-lane col group
    int r = r0 + rbase + rr;
    if (r < N) {
      __half2 lo = __floats2half2_rn(aa.x, aa.y);
      __half2 hi = __floats2half2_rn(aa.z, aa.w);
      __half2* dst = (__half2*)(H16 + (size_t)r * 128 + 4 * colgrp);
      dst[0] = lo; dst[1] = hi;
      if (colgrp == 0) rnorm[r] = rsqrtf(s + 1e-12f);
    }
  }
}

// ---------------- fused attention softmax + aggregate + relu ---------------
// One wave per dst node, 4 groups x 16 lanes; each group scores a different
// edge; sublane l holds dims 8l..8l+7 (one 16B fp16 gather). 1-deep prefetch.
__global__ __launch_bounds__(256) void agg_kernel(
    const __half* __restrict__ H16, const float* __restrict__ rnorm,
    const float* __restrict__ beta_p, const int* __restrict__ offsets,
    const int* __restrict__ csr_src, float* __restrict__ Y, int N) {
  int wid = (blockIdx.x * 256 + threadIdx.x) >> 6;
  int lane = threadIdx.x & 63;
  if (wid >= N) return;
  int g = lane >> 4;
  int l = lane & 15;
  const float4* H4 = (const float4*)H16;

  float4 hdv = H4[(size_t)wid * 16 + l];
  const __half2* hdp = (const __half2*)&hdv;
  float2 d0 = __half22float2(hdp[0]);
  float2 d1 = __half22float2(hdp[1]);
  float2 d2 = __half22float2(hdp[2]);
  float2 d3 = __half22float2(hdp[3]);
  float rdb = rnorm[wid] * beta_p[0];

  int e0 = offsets[wid], e1 = offsets[wid + 1];
  float denom = 0.f;
  float acc[8] = {0.f,0.f,0.f,0.f,0.f,0.f,0.f,0.f};

  int e = e0 + g;
  bool valid = e < e1;
  int s = valid ? csr_src[e] : wid;
  float4 hv = H4[(size_t)s * 16 + l];
  float rs = rnorm[s];

  for (int eb = e0; eb < e1; eb += 4) {
    int en = e + 4;
    bool vn = en < e1;
    int sn = vn ? csr_src[en] : wid;
    float4 hvn = H4[(size_t)sn * 16 + l];
    float rsn = rnorm[sn];

    const __half2* hp = (const __half2*)&hv;
    float2 q0 = __half22float2(hp[0]);
    float2 q1 = __half22float2(hp[1]);
    float2 q2 = __half22float2(hp[2]);
    float2 q3 = __half22float2(hp[3]);
    float p = q0.x*d0.x + q0.y*d0.y + q1.x*d1.x + q1.y*d1.y
            + q2.x*d2.x + q2.y*d2.y + q3.x*d3.x + q3.y*d3.y;
    p += __shfl_xor(p, 1);
    p += __shfl_xor(p, 2);
    p += __shfl_xor(p, 4);
    p += __shfl_xor(p, 8);
    float w = valid ? __expf(p * rdb * rs) : 0.f;
    denom += w;
    acc[0] += w*q0.x; acc[1] += w*q0.y; acc[2] += w*q1.x; acc[3] += w*q1.y;
    acc[4] += w*q2.x; acc[5] += w*q2.y; acc[6] += w*q3.x; acc[7] += w*q3.y;

    e = en; valid = vn; s = sn; hv = hvn; rs = rsn;
  }

  #pragma unroll
  for (int m = 16; m <= 32; m <<= 1) {
    denom += __shfl_xor(denom, m);
    #pragma unroll
    for (int j = 0; j < 8; ++j) acc[j] += __shfl_xor(acc[j], m);
  }
  if (g == 0) {
    float inv = 1.0f / denom;
    float4 o0, o1;
    o0.x = fmaxf(acc[0]*inv, 0.f); o0.y = fmaxf(acc[1]*inv, 0.f);
    o0.z = fmaxf(acc[2]*inv, 0.f); o0.w = fmaxf(acc[3]*inv, 0.f);
    o1.x = fmaxf(acc[4]*inv, 0.f); o1.y = fmaxf(acc[5]*inv, 0.f);
    o1.z = fmaxf(acc[6]*inv, 0.f); o1.w = fmaxf(acc[7]*inv, 0.f);
    ((float4*)Y)[(size_t)wid * 32 + 2 * l] = o0;
    ((float4*)Y)[(size_t)wid * 32 + 2 * l + 1] = o1;
  }
}

// ---------------- launcher -------------------------------------------------
extern "C" void kernel_launch(void* const* d_in, const int* in_sizes, int n_in,
                              void* d_out, int out_size, void* d_ws, size_t ws_size,
                              hipStream_t stream) {
  const float* x     = (const float*)d_in[0];
  const void*  ei    = d_in[1];
  const float* W1    = (const float*)d_in[2];
  const float* b1    = (const float*)d_in[3];
  const float* beta1 = (const float*)d_in[4];
  const float* W2    = (const float*)d_in[5];
  const float* b2    = (const float*)d_in[6];
  const float* beta2 = (const float*)d_in[7];
  float* out = (float*)d_out;

  int N = in_sizes[0] / FDIM;
  int E = in_sizes[1] / 2;

  char* p = (char*)d_ws;
  auto alloc = [&](size_t bytes) {
    char* r = p; p += (bytes + 255) & ~size_t(255); return r;
  };
  int*    counts  = (int*)alloc(sizeof(int) * N);
  int*    offsets = (int*)alloc(sizeof(int) * (N + 1));
  int*    bsum    = (int*)alloc(sizeof(int) * 256);
  int*    src32   = (int*)alloc(sizeof(int) * E);
  int*    dst32   = (int*)alloc(sizeof(int) * E);
  int*    rank    = (int*)alloc(sizeof(int) * E);
  int*    csr     = (int*)alloc(sizeof(int) * E);
  __half* h16     = (__half*)alloc(sizeof(__half) * (size_t)N * FDIM);
  float*  rn      = (float*)alloc(sizeof(float) * N);
  float*  y1      = (float*)alloc(sizeof(float) * (size_t)N * FDIM);

  hipMemsetAsync(counts, 0, sizeof(int) * N, stream);
  int cb = (E + 255) / 256;
  int nb = (N + SCAN_CHUNK - 1) / SCAN_CHUNK;
  convert_count_kernel<<<cb, 256, 0, stream>>>(ei, E, src32, dst32, rank, counts);
  scan_a_kernel<<<nb, 256, 0, stream>>>(counts, bsum, N);
  scan_c_kernel<<<nb, 256, 0, stream>>>(counts, bsum, offsets, N, E);
  scatter_kernel<<<cb, 256, 0, stream>>>(src32, dst32, rank, offsets, E, csr);

  int gb = (N + 63) / 64;
  int ab = (N + 3) / 4;  // 4 waves (dst nodes) per 256-thread block
  gemm_norm_kernel<<<gb, 256, 0, stream>>>(x, W1, b1, h16, rn, N);
  agg_kernel<<<ab, 256, 0, stream>>>(h16, rn, beta1, offsets, csr, y1, N);
  gemm_norm_kernel<<<gb, 256, 0, stream>>>(y1, W2, b2, h16, rn, N);
  agg_kernel<<<ab, 256, 0, stream>>>(h16, rn, beta2, offsets, csr, out, N);
}

// Round 5
// 256.566 us; speedup vs baseline: 2.0705x; 1.0746x over previous
//
#include <hip/hip_runtime.h>
#include <hip/hip_bf16.h>
#include <hip/hip_fp16.h>

// AGNN 2-layer encoder: N=50000 nodes, E=850000 edges (w/ self-loops), D=H=128.
// R5: padded histogram counters (1 per 128B line: kills per-line atomic
// serialization), convert fused into gemm1 dispatch (grid-split), fp16 y1.

#define FDIM 128
#define SCAN_CHUNK 2048   // 256 threads x 8 elems
#define CSTRIDE 32        // ints per histogram counter (128B line)

// ---------------- H = X@W + b, fused row L2-norm, fp16 output --------------
// 64-row tile per block, X staged transposed in LDS (stride 72), 8x4 thread
// tile, f32 accumulate. Templated input dtype (f32 layer1, fp16 layer2).
template <typename TIN>
__device__ __forceinline__ void gemm_body(
    const TIN* __restrict__ X, const float* __restrict__ Wg,
    const float* __restrict__ bias, __half* __restrict__ H16,
    float* __restrict__ rnorm, int N, int bid) {
  __shared__ float xt[128][72];  // [k][row], 36.9KB
  int tid = threadIdx.x;
  int wv = tid >> 6, lane = tid & 63;
  int rowgrp = lane >> 5;
  int colgrp = lane & 31;
  int rbase = wv * 16 + rowgrp * 8;
  float4 bj = ((const float4*)bias)[colgrp];
  int r0 = bid * 64;

  for (int idx = tid; idx < 64 * 128; idx += 256) {
    int rr = idx >> 7, cc = idx & 127;
    int r = r0 + rr; if (r >= N) r = N - 1;
    xt[cc][rr] = (float)X[(size_t)r * 128 + cc];
  }
  __syncthreads();

  float4 a[8];
  #pragma unroll
  for (int rr = 0; rr < 8; ++rr) a[rr] = bj;

  #pragma unroll 4
  for (int k = 0; k < 128; ++k) {
    float4 w = *(const float4*)(Wg + k * 128 + 4 * colgrp);
    float4 xv0 = *(const float4*)&xt[k][rbase];
    float4 xv1 = *(const float4*)&xt[k][rbase + 4];
    a[0].x += xv0.x*w.x; a[0].y += xv0.x*w.y; a[0].z += xv0.x*w.z; a[0].w += xv0.x*w.w;
    a[1].x += xv0.y*w.x; a[1].y += xv0.y*w.y; a[1].z += xv0.y*w.z; a[1].w += xv0.y*w.w;
    a[2].x += xv0.z*w.x; a[2].y += xv0.z*w.y; a[2].z += xv0.z*w.z; a[2].w += xv0.z*w.w;
    a[3].x += xv0.w*w.x; a[3].y += xv0.w*w.y; a[3].z += xv0.w*w.z; a[3].w += xv0.w*w.w;
    a[4].x += xv1.x*w.x; a[4].y += xv1.x*w.y; a[4].z += xv1.x*w.z; a[4].w += xv1.x*w.w;
    a[5].x += xv1.y*w.x; a[5].y += xv1.y*w.y; a[5].z += xv1.y*w.z; a[5].w += xv1.y*w.w;
    a[6].x += xv1.z*w.x; a[6].y += xv1.z*w.y; a[6].z += xv1.z*w.z; a[6].w += xv1.z*w.w;
    a[7].x += xv1.w*w.x; a[7].y += xv1.w*w.y; a[7].z += xv1.w*w.z; a[7].w += xv1.w*w.w;
  }

  #pragma unroll
  for (int rr = 0; rr < 8; ++rr) {
    float4 aa = a[rr];
    float s = aa.x*aa.x + aa.y*aa.y + aa.z*aa.z + aa.w*aa.w;
    #pragma unroll
    for (int m = 16; m; m >>= 1) s += __shfl_xor(s, m);  // 32-lane col group
    int r = r0 + rbase + rr;
    if (r < N) {
      __half2 lo = __floats2half2_rn(aa.x, aa.y);
      __half2 hi = __floats2half2_rn(aa.z, aa.w);
      __half2* dst = (__half2*)(H16 + (size_t)r * 128 + 4 * colgrp);
      dst[0] = lo; dst[1] = hi;
      if (colgrp == 0) rnorm[r] = rsqrtf(s + 1e-12f);
    }
  }
}

// ------- convert body: edges -> int32, padded histogram + rank -------------
__device__ __forceinline__ void convert_body(
    const void* __restrict__ ei, int E,
    int* __restrict__ src32, int* __restrict__ dst32,
    int* __restrict__ rank, int* __restrict__ counts, int cbid) {
  const int* eii = (const int*)ei;
  int lane = threadIdx.x & 63;
  int ok = (lane < 32) ? (eii[2 * lane + 1] == 0) : 1;
  bool is64 = (__ballot(ok) == ~0ull);

  int e = cbid * 256 + threadIdx.x;
  if (e >= E) return;
  int s, d;
  if (is64) {
    const long long* p = (const long long*)ei;
    s = (int)p[e]; d = (int)p[E + e];
  } else {
    s = eii[e]; d = eii[E + e];
  }
  src32[e] = s; dst32[e] = d;
  rank[e] = atomicAdd(&counts[d * CSTRIDE], 1);  // old value = within-dst slot
}

// ------- fused dispatch: gemm1 blocks [0,GB) + convert blocks [GB,GB+CB) ---
__global__ __launch_bounds__(256) void gemm1_convert_kernel(
    const float* __restrict__ X, const float* __restrict__ Wg,
    const float* __restrict__ bias, __half* __restrict__ H16,
    float* __restrict__ rnorm, int N, int GB,
    const void* __restrict__ ei, int E,
    int* __restrict__ src32, int* __restrict__ dst32,
    int* __restrict__ rank, int* __restrict__ counts) {
  if ((int)blockIdx.x < GB)
    gemm_body<float>(X, Wg, bias, H16, rnorm, N, blockIdx.x);
  else
    convert_body(ei, E, src32, dst32, rank, counts, blockIdx.x - GB);
}

// ------- standalone gemm (layer 2, fp16 input) -----------------------------
__global__ __launch_bounds__(256) void gemm_norm_h_kernel(
    const __half* __restrict__ X, const float* __restrict__ Wg,
    const float* __restrict__ bias, __half* __restrict__ H16,
    float* __restrict__ rnorm, int N) {
  gemm_body<__half>(X, Wg, bias, H16, rnorm, N, blockIdx.x);
}

// ------- scan stage A: per-chunk sums (strided padded counts) --------------
__global__ __launch_bounds__(256) void scan_a_kernel(
    const int* __restrict__ counts, int* __restrict__ bsum, int N) {
  __shared__ int ws[4];
  int tid = threadIdx.x;
  int i0 = blockIdx.x * SCAN_CHUNK + tid * 8;
  int s = 0;
  #pragma unroll
  for (int j = 0; j < 8; ++j)
    if (i0 + j < N) s += counts[(size_t)(i0 + j) * CSTRIDE];
  #pragma unroll
  for (int m = 32; m; m >>= 1) s += __shfl_xor(s, m);
  int lane = tid & 63, wv = tid >> 6;
  if (lane == 0) ws[wv] = s;
  __syncthreads();
  if (tid == 0) bsum[blockIdx.x] = ws[0] + ws[1] + ws[2] + ws[3];
}

// ------- scan stage C: per-chunk exclusive scan + cross-chunk base ---------
__global__ __launch_bounds__(256) void scan_c_kernel(
    const int* __restrict__ counts, const int* __restrict__ bsum,
    int* __restrict__ offsets, int N, int E) {
  __shared__ int wsum[4];
  int tid = threadIdx.x, lane = tid & 63, wv = tid >> 6;

  int bse = 0;
  for (int j = lane; j < (int)blockIdx.x; j += 64) bse += bsum[j];
  #pragma unroll
  for (int m = 32; m; m >>= 1) bse += __shfl_xor(bse, m);

  int i0 = blockIdx.x * SCAN_CHUNK + tid * 8;
  int v[8];
  #pragma unroll
  for (int j = 0; j < 8; ++j)
    v[j] = (i0 + j < N) ? counts[(size_t)(i0 + j) * CSTRIDE] : 0;
  int pre[8], t = 0;
  #pragma unroll
  for (int j = 0; j < 8; ++j) { pre[j] = t; t += v[j]; }
  int x = t;
  #pragma unroll
  for (int off = 1; off < 64; off <<= 1) {
    int u = __shfl_up(x, off);
    if (lane >= off) x += u;
  }
  if (lane == 63) wsum[wv] = x;
  __syncthreads();
  int waveoff = 0;
  #pragma unroll
  for (int w = 0; w < 4; ++w) if (w < wv) waveoff += wsum[w];
  int ebase = bse + waveoff + (x - t);
  #pragma unroll
  for (int j = 0; j < 8; ++j) {
    int i = i0 + j;
    if (i < N) offsets[i] = ebase + pre[j];
  }
  if (blockIdx.x == 0 && tid == 0) offsets[N] = E;
}

// ------- atomic-free scatter: pos = offsets[dst] + rank --------------------
__global__ __launch_bounds__(256) void scatter_kernel(
    const int* __restrict__ src32, const int* __restrict__ dst32,
    const int* __restrict__ rank, const int* __restrict__ offsets, int E,
    int* __restrict__ csr_src) {
  int e = blockIdx.x * 256 + threadIdx.x;
  if (e >= E) return;
  csr_src[offsets[dst32[e]] + rank[e]] = src32[e];
}

// ---------------- fused attention softmax + aggregate + relu ---------------
// One wave per dst node, 4 groups x 16 lanes; each group scores a different
// edge; sublane l holds dims 8l..8l+7 (one 16B fp16 gather). 1-deep prefetch.
// Output: fp16 (layer1, feeds gemm2) or f32 (layer2, final).
template <bool OUT_HALF>
__global__ __launch_bounds__(256) void agg_kernel(
    const __half* __restrict__ H16, const float* __restrict__ rnorm,
    const float* __restrict__ beta_p, const int* __restrict__ offsets,
    const int* __restrict__ csr_src, void* __restrict__ Yp, int N) {
  int wid = (blockIdx.x * 256 + threadIdx.x) >> 6;
  int lane = threadIdx.x & 63;
  if (wid >= N) return;
  int g = lane >> 4;
  int l = lane & 15;
  const float4* H4 = (const float4*)H16;

  float4 hdv = H4[(size_t)wid * 16 + l];
  const __half2* hdp = (const __half2*)&hdv;
  float2 d0 = __half22float2(hdp[0]);
  float2 d1 = __half22float2(hdp[1]);
  float2 d2 = __half22float2(hdp[2]);
  float2 d3 = __half22float2(hdp[3]);
  float rdb = rnorm[wid] * beta_p[0];

  int e0 = offsets[wid], e1 = offsets[wid + 1];
  float denom = 0.f;
  float acc[8] = {0.f,0.f,0.f,0.f,0.f,0.f,0.f,0.f};

  int e = e0 + g;
  bool valid = e < e1;
  int s = valid ? csr_src[e] : wid;
  float4 hv = H4[(size_t)s * 16 + l];
  float rs = rnorm[s];

  for (int eb = e0; eb < e1; eb += 4) {
    int en = e + 4;
    bool vn = en < e1;
    int sn = vn ? csr_src[en] : wid;
    float4 hvn = H4[(size_t)sn * 16 + l];
    float rsn = rnorm[sn];

    const __half2* hp = (const __half2*)&hv;
    float2 q0 = __half22float2(hp[0]);
    float2 q1 = __half22float2(hp[1]);
    float2 q2 = __half22float2(hp[2]);
    float2 q3 = __half22float2(hp[3]);
    float p = q0.x*d0.x + q0.y*d0.y + q1.x*d1.x + q1.y*d1.y
            + q2.x*d2.x + q2.y*d2.y + q3.x*d3.x + q3.y*d3.y;
    p += __shfl_xor(p, 1);
    p += __shfl_xor(p, 2);
    p += __shfl_xor(p, 4);
    p += __shfl_xor(p, 8);
    float w = valid ? __expf(p * rdb * rs) : 0.f;
    denom += w;
    acc[0] += w*q0.x; acc[1] += w*q0.y; acc[2] += w*q1.x; acc[3] += w*q1.y;
    acc[4] += w*q2.x; acc[5] += w*q2.y; acc[6] += w*q3.x; acc[7] += w*q3.y;

    e = en; valid = vn; s = sn; hv = hvn; rs = rsn;
  }

  #pragma unroll
  for (int m = 16; m <= 32; m <<= 1) {
    denom += __shfl_xor(denom, m);
    #pragma unroll
    for (int j = 0; j < 8; ++j) acc[j] += __shfl_xor(acc[j], m);
  }
  if (g == 0) {
    float inv = 1.0f / denom;  // denom > 0 guaranteed by self-loop
    float o[8];
    #pragma unroll
    for (int j = 0; j < 8; ++j) o[j] = fmaxf(acc[j] * inv, 0.f);
    if constexpr (OUT_HALF) {
      float4 pack;
      __half2* hp2 = (__half2*)&pack;
      hp2[0] = __floats2half2_rn(o[0], o[1]);
      hp2[1] = __floats2half2_rn(o[2], o[3]);
      hp2[2] = __floats2half2_rn(o[4], o[5]);
      hp2[3] = __floats2half2_rn(o[6], o[7]);
      ((float4*)Yp)[(size_t)wid * 16 + l] = pack;
    } else {
      float4 o0 = {o[0], o[1], o[2], o[3]};
      float4 o1 = {o[4], o[5], o[6], o[7]};
      ((float4*)Yp)[(size_t)wid * 32 + 2 * l] = o0;
      ((float4*)Yp)[(size_t)wid * 32 + 2 * l + 1] = o1;
    }
  }
}

// ---------------- launcher -------------------------------------------------
extern "C" void kernel_launch(void* const* d_in, const int* in_sizes, int n_in,
                              void* d_out, int out_size, void* d_ws, size_t ws_size,
                              hipStream_t stream) {
  const float* x     = (const float*)d_in[0];
  const void*  ei    = d_in[1];
  const float* W1    = (const float*)d_in[2];
  const float* b1    = (const float*)d_in[3];
  const float* beta1 = (const float*)d_in[4];
  const float* W2    = (const float*)d_in[5];
  const float* b2    = (const float*)d_in[6];
  const float* beta2 = (const float*)d_in[7];

  int N = in_sizes[0] / FDIM;
  int E = in_sizes[1] / 2;

  char* p = (char*)d_ws;
  auto alloc = [&](size_t bytes) {
    char* r = p; p += (bytes + 255) & ~size_t(255); return r;
  };
  int*    counts  = (int*)alloc(sizeof(int) * (size_t)N * CSTRIDE);
  int*    offsets = (int*)alloc(sizeof(int) * (N + 1));
  int*    bsum    = (int*)alloc(sizeof(int) * 256);
  int*    src32   = (int*)alloc(sizeof(int) * E);
  int*    dst32   = (int*)alloc(sizeof(int) * E);
  int*    rank    = (int*)alloc(sizeof(int) * E);
  int*    csr     = (int*)alloc(sizeof(int) * E);
  __half* h16     = (__half*)alloc(sizeof(__half) * (size_t)N * FDIM);
  float*  rn      = (float*)alloc(sizeof(float) * N);
  __half* y1h     = (__half*)alloc(sizeof(__half) * (size_t)N * FDIM);

  hipMemsetAsync(counts, 0, sizeof(int) * (size_t)N * CSTRIDE, stream);

  int cb = (E + 255) / 256;
  int gb = (N + 63) / 64;
  int nb = (N + SCAN_CHUNK - 1) / SCAN_CHUNK;
  int ab = (N + 3) / 4;  // 4 waves (dst nodes) per 256-thread block

  // gemm1 (VALU/LDS-bound) overlapped with convert (atomic/memory-bound)
  gemm1_convert_kernel<<<gb + cb, 256, 0, stream>>>(
      x, W1, b1, h16, rn, N, gb, ei, E, src32, dst32, rank, counts);
  scan_a_kernel<<<nb, 256, 0, stream>>>(counts, bsum, N);
  scan_c_kernel<<<nb, 256, 0, stream>>>(counts, bsum, offsets, N, E);
  scatter_kernel<<<cb, 256, 0, stream>>>(src32, dst32, rank, offsets, E, csr);

  agg_kernel<true><<<ab, 256, 0, stream>>>(h16, rn, beta1, offsets, csr, y1h, N);
  gemm_norm_h_kernel<<<gb, 256, 0, stream>>>(y1h, W2, b2, h16, rn, N);
  agg_kernel<false><<<ab, 256, 0, stream>>>(h16, rn, beta2, offsets, csr, d_out, N);
}